// Round 1
// baseline (738.800 us; speedup 1.0000x reference)
//
#include <hip/hip_runtime.h>
#include <math.h>

#define NGRAPH 64
#define NPER   256
#define NNODE  (NGRAPH*NPER)      // 16384
#define CDIM   64
#define NELEM  10
#define NEDGE  (NNODE*24)         // 393216
#define RMAX2  25.0f

__device__ __forceinline__ float silu_f(float x){ return x/(1.f+__expf(-x)); }

// ---------------------------------------------------------------- init
__global__ __launch_bounds__(64) void k_init(
    const float* __restrict__ attrs, const float* __restrict__ W_embed,
    const float* __restrict__ E0, float* __restrict__ s_cur,
    float* __restrict__ feats, float* __restrict__ out_ctr, float* __restrict__ out_ne)
{
  int n = blockIdx.x, c = threadIdx.x;
  float s = 0.f;
  #pragma unroll
  for (int k = 0; k < NELEM; k++) s += attrs[n*NELEM+k]*W_embed[k*CDIM+c];
  s_cur[n*CDIM+c] = s;
  feats[(size_t)n*9*CDIM + c] = s;
  #pragma unroll
  for (int m = 1; m < 9; m++) feats[((size_t)n*9+m)*CDIM+c] = 0.f;
  if (c == 0){
    float ev = 0.f;
    #pragma unroll
    for (int k = 0; k < NELEM; k++) ev += attrs[n*NELEM+k]*E0[k];
    out_ne[n] = ev;
    atomicAdd(&out_ctr[(n>>8)*3], ev);
  }
}

// ---------------------------------------------------------------- edge geometry
__global__ __launch_bounds__(256) void k_geom(
    const int* __restrict__ ei, const float* __restrict__ pos,
    float* __restrict__ sh, float* __restrict__ ef)
{
  int e = blockIdx.x*256 + threadIdx.x;
  int s = ei[e], d = ei[NEDGE+e];
  float vx = pos[d*3]-pos[s*3], vy = pos[d*3+1]-pos[s*3+1], vz = pos[d*3+2]-pos[s*3+2];
  float r2 = vx*vx+vy*vy+vz*vz;
  if (r2 >= RMAX2) return;                 // pruned: never referenced by CSR
  float r = sqrtf(r2);
  float inv = 1.f/fmaxf(r, 1e-9f);
  float x_ = vx*inv, y_ = vy*inv, z_ = vz*inv;
  const float s3 = 1.7320508075688772f, s15 = 3.872983346207417f, s5 = 2.2360679774997896f;
  float* she = sh + (size_t)e*9;
  she[0] = 1.f;        she[1] = s3*x_;      she[2] = s3*y_;       she[3] = s3*z_;
  she[4] = s15*x_*y_;  she[5] = s15*y_*z_;  she[6] = 0.5f*s5*(3.f*z_*z_-1.f);
  she[7] = s15*x_*z_;  she[8] = 0.5f*s15*(x_*x_-y_*y_);
  float xx = r*0.2f;
  float x2 = xx*xx;
  float x5 = x2*x2*xx;
  float env = 1.f - 21.f*x5 + 35.f*x5*xx - 15.f*x5*x2;
  float pref = 0.6324555320336759f*inv*env;
  float* efe = ef + (size_t)e*8;
  const float PI_ = 3.14159265358979323846f;
  #pragma unroll
  for (int b = 0; b < 8; b++) efe[b] = pref*sinf((float)(b+1)*PI_*xx);
}

// ---------------------------------------------------------------- CSR build
__global__ __launch_bounds__(256) void k_count(
    const int* __restrict__ ei, const float* __restrict__ pos, int* __restrict__ deg)
{
  int e = blockIdx.x*256 + threadIdx.x;
  int s = ei[e], d = ei[NEDGE+e];
  float vx = pos[d*3]-pos[s*3], vy = pos[d*3+1]-pos[s*3+1], vz = pos[d*3+2]-pos[s*3+2];
  if (vx*vx+vy*vy+vz*vz < RMAX2) atomicAdd(&deg[d], 1);
}

__global__ __launch_bounds__(1024) void k_scan(const int* __restrict__ deg, int* __restrict__ offs)
{
  __shared__ int sums[1024];
  int t = threadIdx.x;
  int loc[16];
  int s = 0, base = t*16;
  #pragma unroll
  for (int i = 0; i < 16; i++){ loc[i] = s; s += deg[base+i]; }
  sums[t] = s;
  __syncthreads();
  for (int off = 1; off < 1024; off <<= 1){
    int v = (t >= off) ? sums[t-off] : 0;
    __syncthreads();
    sums[t] += v;
    __syncthreads();
  }
  int pre = (t > 0) ? sums[t-1] : 0;
  #pragma unroll
  for (int i = 0; i < 16; i++) offs[base+i] = pre + loc[i];
  if (t == 1023) offs[NNODE] = pre + s;
}

__global__ __launch_bounds__(256) void k_fill(
    const int* __restrict__ ei, const float* __restrict__ pos,
    const int* __restrict__ offs, int* __restrict__ cursor, int* __restrict__ el)
{
  int e = blockIdx.x*256 + threadIdx.x;
  int s = ei[e], d = ei[NEDGE+e];
  float vx = pos[d*3]-pos[s*3], vy = pos[d*3+1]-pos[s*3+1], vz = pos[d*3+2]-pos[s*3+2];
  if (vx*vx+vy*vy+vz*vz < RMAX2){
    int p = atomicAdd(&cursor[d], 1);
    el[offs[d]+p] = e;
  }
}

// ---------------------------------------------------------------- radial MLP -> R (active edges only)
#define ACC_ZERO() do{ _Pragma("unroll") for(int i_=0;i_<4;i_++){ _Pragma("unroll") for(int j_=0;j_<4;j_++) acc[i_][j_]=0.f; } }while(0)
#define GEMM_STEP(H,KMAX) do{ _Pragma("unroll 8") for(int k_=0;k_<KMAX;k_++){ \
  float4 h_ = *(const float4*)&H[k_*64+e4]; \
  float4 w_ = *(const float4*)&Wl[k_*64+c4]; \
  acc[0][0]+=h_.x*w_.x; acc[0][1]+=h_.x*w_.y; acc[0][2]+=h_.x*w_.z; acc[0][3]+=h_.x*w_.w; \
  acc[1][0]+=h_.y*w_.x; acc[1][1]+=h_.y*w_.y; acc[1][2]+=h_.y*w_.z; acc[1][3]+=h_.y*w_.w; \
  acc[2][0]+=h_.z*w_.x; acc[2][1]+=h_.z*w_.y; acc[2][2]+=h_.z*w_.z; acc[2][3]+=h_.z*w_.w; \
  acc[3][0]+=h_.w*w_.x; acc[3][1]+=h_.w*w_.y; acc[3][2]+=h_.w*w_.z; acc[3][3]+=h_.w*w_.w; } }while(0)
#define SILU_ACC() do{ _Pragma("unroll") for(int i_=0;i_<4;i_++){ _Pragma("unroll") for(int j_=0;j_<4;j_++) acc[i_][j_]=silu_f(acc[i_][j_]); } }while(0)
#define STORE_H(HOUT) do{ _Pragma("unroll") for(int j_=0;j_<4;j_++){ \
  *(float4*)&HOUT[(c4+j_)*64+e4] = make_float4(acc[0][j_],acc[1][j_],acc[2][j_],acc[3][j_]); } }while(0)

__global__ __launch_bounds__(256) void k_R(
    const float* __restrict__ ef, const int* __restrict__ el, const int* __restrict__ nact_p,
    const float* __restrict__ W1, const float* __restrict__ W2,
    const float* __restrict__ W3, const float* __restrict__ W4,
    float* __restrict__ Rout)
{
  __shared__ __align__(16) float Wl[4096];
  __shared__ __align__(16) float hA[4096];
  __shared__ __align__(16) float hB[4096];
  int nact = *nact_p;
  int ebase = blockIdx.x*64;
  if (ebase >= nact) return;
  int tid = threadIdx.x;
  for (int i = tid; i < 512; i += 256){
    int eL = i>>3, b = i&7;
    int idx = ebase+eL; if (idx > nact-1) idx = nact-1;
    int ge = el[idx];
    hA[b*64+eL] = ef[(size_t)ge*8+b];
  }
  for (int i = tid; i < 512; i += 256) Wl[i] = W1[i];
  __syncthreads();
  int c4 = (tid & 15)*4, e4 = (tid >> 4)*4;
  float acc[4][4];
  // layer 1 (K=8) + silu
  ACC_ZERO(); GEMM_STEP(hA, 8); SILU_ACC();
  __syncthreads();
  STORE_H(hB);
  for (int i = tid; i < 1024; i += 256) ((float4*)Wl)[i] = ((const float4*)W2)[i];
  __syncthreads();
  // layer 2 + silu
  ACC_ZERO(); GEMM_STEP(hB, 64); SILU_ACC();
  __syncthreads();
  STORE_H(hA);
  for (int i = tid; i < 1024; i += 256) ((float4*)Wl)[i] = ((const float4*)W3)[i];
  __syncthreads();
  // layer 3 + silu
  ACC_ZERO(); GEMM_STEP(hA, 64); SILU_ACC();
  __syncthreads();
  STORE_H(hB);
  for (int i = tid; i < 1024; i += 256) ((float4*)Wl)[i] = ((const float4*)W4)[i];
  __syncthreads();
  // layer 4, no silu, store to global
  ACC_ZERO(); GEMM_STEP(hB, 64);
  #pragma unroll
  for (int i = 0; i < 4; i++){
    int idx = ebase+e4+i; if (idx > nact-1) idx = nact-1;
    int ge = el[idx];
    *(float4*)&Rout[(size_t)ge*64+c4] = make_float4(acc[i][0],acc[i][1],acc[i][2],acc[i][3]);
  }
}

// ---------------------------------------------------------------- gather + mix + product + epilogue
__global__ __launch_bounds__(256) void k_gather(
    const float* __restrict__ Rbuf, const float* __restrict__ s_cur, float* __restrict__ s_nxt,
    const float* __restrict__ sh, const int* __restrict__ el, const int* __restrict__ offs,
    const int* __restrict__ srcA, const float* __restrict__ attrs, float* __restrict__ feats,
    const float* __restrict__ WmixT, const float* __restrict__ WscT, const float* __restrict__ w2T,
    const float* __restrict__ w3T, const float* __restrict__ WqT, const float* __restrict__ Wr0,
    const float* __restrict__ Wh, const float* __restrict__ Wo,
    float* __restrict__ out_ne, float* __restrict__ out_ctr, float* __restrict__ out_q, int t)
{
  __shared__ __align__(16) float WT[3*4160];    // [l][c*65+d], pad 65 -> conflict-free both ways
  __shared__ __align__(16) float aggS[4][768];  // per-wave [c*12+m], stride 12 keeps float4 align
  __shared__ float f0S[4][64];
  __shared__ float hS[4][16];
  int tid = threadIdx.x;
  for (int i = tid; i < 3*64*64; i += 256){
    int l = i>>12, rem = i&4095, d = rem>>6, c = rem&63;
    WT[l*4160 + c*65 + d] = WmixT[i];
  }
  __syncthreads();
  int wv = tid>>6, ln = tid&63;
  for (int it = 0; it < 2; ++it){
    int n = blockIdx.x*8 + it*4 + wv;
    int g = n>>8;
    int beg = offs[n], end = offs[n+1];
    float acc[9] = {0,0,0,0,0,0,0,0,0};
    for (int p2 = beg; p2 < end; ++p2){
      int e = __builtin_amdgcn_readfirstlane(el[p2]);
      int s = __builtin_amdgcn_readfirstlane(srcA[e]);
      float pr = Rbuf[(size_t)e*64+ln] * s_cur[s*64+ln];
      const float* she = sh + (size_t)e*9;
      #pragma unroll
      for (int m = 0; m < 9; m++) acc[m] += pr*she[m];
    }
    #pragma unroll
    for (int m = 0; m < 9; m++) aggS[wv][ln*12+m] = acc[m]*(1.f/24.f);
    __syncthreads();
    float mx[9] = {0,0,0,0,0,0,0,0,0};
    #pragma unroll 4
    for (int c = 0; c < 64; ++c){
      float4 a0 = *(const float4*)&aggS[wv][c*12];
      float4 a1 = *(const float4*)&aggS[wv][c*12+4];
      float a8  = aggS[wv][c*12+8];
      float w0 = WT[c*65+ln];
      float w1 = WT[4160 + c*65+ln];
      float wc = WT[8320 + c*65+ln];
      mx[0] += a0.x*w0;
      mx[1] += a0.y*w1; mx[2] += a0.z*w1; mx[3] += a0.w*w1;
      mx[4] += a1.x*wc; mx[5] += a1.y*wc; mx[6] += a1.z*wc; mx[7] += a1.w*wc;
      mx[8] += a8*wc;
    }
    float g2 = 0.f, g3 = 0.f, wsc = 0.f;
    #pragma unroll
    for (int k = 0; k < NELEM; k++){
      float a = attrs[n*NELEM+k];
      g2 += a*w2T[k*64+ln]; g3 += a*w3T[k*64+ln]; wsc += a*WscT[k*64+ln];
    }
    float s0 = mx[0];
    float factor = 1.f + g2*s0 + g3*s0*s0;
    float f0 = 0.f;
    #pragma unroll
    for (int m = 0; m < 9; m++){
      size_t idx = ((size_t)n*9+m)*64+ln;
      float fnew = mx[m]*factor + feats[idx]*wsc;
      feats[idx] = fnew;
      if (m == 0) f0 = fnew;
    }
    s_nxt[n*64+ln] = f0;
    float qv = f0*WqT[ln];
    #pragma unroll
    for (int o = 32; o > 0; o >>= 1) qv += __shfl_down(qv, o, 64);
    float nev = 0.f;
    if (t == 0){
      nev = f0*Wr0[ln];
      #pragma unroll
      for (int o = 32; o > 0; o >>= 1) nev += __shfl_down(nev, o, 64);
    }
    f0S[wv][ln] = f0;
    __syncthreads();
    if (t == 1 && ln < 16){
      float h = 0.f;
      #pragma unroll 8
      for (int dd = 0; dd < 64; dd++) h += f0S[wv][dd]*Wh[dd*16+ln];
      hS[wv][ln] = silu_f(h);
    }
    __syncthreads();
    if (ln == 0){
      out_q[n] += qv;
      if (t == 0){
        out_ne[n] += nev;
        atomicAdd(&out_ctr[g*3+1], nev);
      } else {
        float ne2 = 0.f;
        #pragma unroll
        for (int j = 0; j < 16; j++) ne2 += hS[wv][j]*Wo[j];
        out_ne[n] += ne2;
        atomicAdd(&out_ctr[g*3+2], ne2);
      }
    }
    __syncthreads();   // protect aggS/f0S/hS before next node iteration
  }
}

// ---------------------------------------------------------------- Coulomb + dipole + total
__global__ __launch_bounds__(256) void k_coul(
    const float* __restrict__ q, const float* __restrict__ pos,
    const float* __restrict__ ctr, float* __restrict__ te, float* __restrict__ dip)
{
  __shared__ float qs[256], px[256], py[256], pz[256];
  __shared__ float red[16];
  int g = blockIdx.x, i = threadIdx.x, n = g*256+i;
  float qi = q[n];
  float xi = pos[n*3], yi = pos[n*3+1], zi = pos[n*3+2];
  qs[i] = qi; px[i] = xi; py[i] = yi; pz[i] = zi;
  __syncthreads();
  float srow = 0.f;
  for (int j = 0; j < 256; ++j){
    float dx = xi-px[j], dy = yi-py[j], dz = zi-pz[j];
    float r2 = dx*dx+dy*dy+dz*dz + 1e-12f;
    float r = sqrtf(r2);
    float v = erff(0.5f*r)/r;
    srow += (j == i) ? 0.f : qs[j]*v;
  }
  float vals[4] = { qi*srow, qi*xi, qi*yi, qi*zi };
  int wv = i>>6, ln = i&63;
  #pragma unroll
  for (int k = 0; k < 4; k++){
    float v = vals[k];
    #pragma unroll
    for (int o = 32; o > 0; o >>= 1) v += __shfl_down(v, o, 64);
    if (ln == 0) red[wv*4+k] = v;
  }
  __syncthreads();
  if (i == 0){
    float e = 0.f, dx = 0.f, dy = 0.f, dz = 0.f;
    for (int w = 0; w < 4; w++){ e += red[w*4]; dx += red[w*4+1]; dy += red[w*4+2]; dz += red[w*4+3]; }
    te[g] = ctr[g*3] + ctr[g*3+1] + ctr[g*3+2] + 0.5f*e;
    dip[g*3] = dx; dip[g*3+1] = dy; dip[g*3+2] = dz;
  }
}

// ---------------------------------------------------------------- launch
extern "C" void kernel_launch(void* const* d_in, const int* in_sizes, int n_in,
                              void* d_out, int out_size, void* d_ws, size_t ws_size,
                              hipStream_t stream)
{
  (void)in_sizes; (void)n_in; (void)out_size; (void)ws_size;
  const float* attrs   = (const float*)d_in[0];
  const float* pos     = (const float*)d_in[1];
  const int*   ei      = (const int*)d_in[2];
  const float* W_embed = (const float*)d_in[4];
  const float* E0      = (const float*)d_in[5];
  const float* rW1     = (const float*)d_in[6];
  const float* rW2     = (const float*)d_in[7];
  const float* rW3     = (const float*)d_in[8];
  const float* rW4     = (const float*)d_in[9];
  const float* Wmix    = (const float*)d_in[10];
  const float* Wsc     = (const float*)d_in[11];
  const float* w2      = (const float*)d_in[12];
  const float* w3      = (const float*)d_in[13];
  const float* Wr0     = (const float*)d_in[14];
  const float* Wh      = (const float*)d_in[15];
  const float* Wo      = (const float*)d_in[16];
  const float* Wq      = (const float*)d_in[17];

  float* ws    = (float*)d_ws;
  float* sh    = ws;                                   // NEDGE*9
  float* ef    = sh    + (size_t)NEDGE*9;              // NEDGE*8
  float* s_cur = ef    + (size_t)NEDGE*8;              // NNODE*64
  float* s_nxt = s_cur + (size_t)NNODE*CDIM;           // NNODE*64
  float* feats = s_nxt + (size_t)NNODE*CDIM;           // NNODE*64*9
  float* Rbuf  = feats + (size_t)NNODE*CDIM*9;         // NEDGE*64
  int*   deg   = (int*)(Rbuf + (size_t)NEDGE*CDIM);    // NNODE
  int*   offs  = deg    + NNODE;                       // NNODE+1
  int*   cursor= offs   + NNODE+1;                     // NNODE
  int*   el    = cursor + NNODE;                       // NEDGE

  float* out_te  = (float*)d_out;
  float* out_ne  = out_te  + NGRAPH;
  float* out_ctr = out_ne  + NNODE;
  float* out_q   = out_ctr + NGRAPH*3;
  float* out_dip = out_q   + NNODE;

  hipMemsetAsync(d_out, 0, sizeof(float)*(size_t)(NGRAPH + NNODE + NGRAPH*3 + NNODE + NGRAPH*3), stream);
  hipMemsetAsync(deg, 0, sizeof(int)*(size_t)NNODE, stream);
  hipMemsetAsync(cursor, 0, sizeof(int)*(size_t)NNODE, stream);

  k_init <<<NNODE, 64, 0, stream>>>(attrs, W_embed, E0, s_cur, feats, out_ctr, out_ne);
  k_geom <<<NEDGE/256, 256, 0, stream>>>(ei, pos, sh, ef);
  k_count<<<NEDGE/256, 256, 0, stream>>>(ei, pos, deg);
  k_scan <<<1, 1024, 0, stream>>>(deg, offs);
  k_fill <<<NEDGE/256, 256, 0, stream>>>(ei, pos, offs, cursor, el);

  for (int t = 0; t < 2; t++){
    const float* scur = t ? s_nxt : s_cur;
    float*       snxt = t ? s_cur : s_nxt;
    k_R<<<NEDGE/64, 256, 0, stream>>>(ef, el, offs+NNODE,
        rW1 + t*8*64, rW2 + t*64*64, rW3 + t*64*64, rW4 + t*64*CDIM, Rbuf);
    k_gather<<<NNODE/8, 256, 0, stream>>>(Rbuf, scur, snxt, sh, el, offs, ei,
        attrs, feats, Wmix + t*3*64*64, Wsc + t*NELEM*CDIM, w2 + t*NELEM*CDIM,
        w3 + t*NELEM*CDIM, Wq + t*CDIM, Wr0, Wh, Wo, out_ne, out_ctr, out_q, t);
  }
  k_coul<<<NGRAPH, 256, 0, stream>>>(out_q, pos, out_ctr, out_te, out_dip);
}

// Round 2
// 561.584 us; speedup vs baseline: 1.3156x; 1.3156x over previous
//
#include <hip/hip_runtime.h>
#include <math.h>

#define NGRAPH 64
#define NPER   256
#define NNODE  (NGRAPH*NPER)      // 16384
#define CDIM   64
#define NELEM  10
#define NEDGE  (NNODE*24)         // 393216
#define RMAX2  25.0f

__device__ __forceinline__ float silu_f(float x){ return x/(1.f+__expf(-x)); }

// ---------------------------------------------------------------- init
__global__ __launch_bounds__(64) void k_init(
    const float* __restrict__ attrs, const float* __restrict__ W_embed,
    const float* __restrict__ E0, float* __restrict__ s_cur,
    float* __restrict__ feats, float* __restrict__ out_ctr, float* __restrict__ out_ne)
{
  int n = blockIdx.x, c = threadIdx.x;
  float s = 0.f;
  #pragma unroll
  for (int k = 0; k < NELEM; k++) s += attrs[n*NELEM+k]*W_embed[k*CDIM+c];
  s_cur[n*CDIM+c] = s;
  feats[(size_t)n*9*CDIM + c] = s;
  #pragma unroll
  for (int m = 1; m < 9; m++) feats[((size_t)n*9+m)*CDIM+c] = 0.f;
  if (c == 0){
    float ev = 0.f;
    #pragma unroll
    for (int k = 0; k < NELEM; k++) ev += attrs[n*NELEM+k]*E0[k];
    out_ne[n] = ev;
    atomicAdd(&out_ctr[(n>>8)*3], ev);
  }
}

// ---------------------------------------------------------------- CSR: count
__global__ __launch_bounds__(256) void k_count(
    const int* __restrict__ ei, const float* __restrict__ pos, int* __restrict__ deg)
{
  int e = blockIdx.x*256 + threadIdx.x;
  int s = ei[e], d = ei[NEDGE+e];
  float vx = pos[d*3]-pos[s*3], vy = pos[d*3+1]-pos[s*3+1], vz = pos[d*3+2]-pos[s*3+2];
  if (vx*vx+vy*vy+vz*vz < RMAX2) atomicAdd(&deg[d], 1);
}

__global__ __launch_bounds__(1024) void k_scan(const int* __restrict__ deg, int* __restrict__ offs)
{
  __shared__ int sums[1024];
  int t = threadIdx.x;
  int loc[16];
  int s = 0, base = t*16;
  #pragma unroll
  for (int i = 0; i < 16; i++){ loc[i] = s; s += deg[base+i]; }
  sums[t] = s;
  __syncthreads();
  for (int off = 1; off < 1024; off <<= 1){
    int v = (t >= off) ? sums[t-off] : 0;
    __syncthreads();
    sums[t] += v;
    __syncthreads();
  }
  int pre = (t > 0) ? sums[t-1] : 0;
  #pragma unroll
  for (int i = 0; i < 16; i++) offs[base+i] = pre + loc[i];
  if (t == 1023) offs[NNODE] = pre + s;
}

// ---------------------------------------------------------------- CSR: fill + geometry (CSR-slot order)
__global__ __launch_bounds__(256) void k_fill(
    const int* __restrict__ ei, const float* __restrict__ pos,
    const int* __restrict__ offs, int* __restrict__ cursor,
    int* __restrict__ srcC, float* __restrict__ efC, float* __restrict__ shC)
{
  int e = blockIdx.x*256 + threadIdx.x;
  int s = ei[e], d = ei[NEDGE+e];
  float vx = pos[d*3]-pos[s*3], vy = pos[d*3+1]-pos[s*3+1], vz = pos[d*3+2]-pos[s*3+2];
  float r2 = vx*vx+vy*vy+vz*vz;
  if (r2 >= RMAX2) return;
  int p = atomicAdd(&cursor[d], 1);
  int slot = offs[d] + p;
  srcC[slot] = s;
  float r = sqrtf(r2);
  float inv = 1.f/fmaxf(r, 1e-9f);
  float x_ = vx*inv, y_ = vy*inv, z_ = vz*inv;
  const float s3 = 1.7320508075688772f, s15 = 3.872983346207417f, s5 = 2.2360679774997896f;
  float* shp = shC + (size_t)slot*12;
  shp[0] = 1.f;        shp[1] = s3*x_;      shp[2] = s3*y_;       shp[3] = s3*z_;
  shp[4] = s15*x_*y_;  shp[5] = s15*y_*z_;  shp[6] = 0.5f*s5*(3.f*z_*z_-1.f);
  shp[7] = s15*x_*z_;  shp[8] = 0.5f*s15*(x_*x_-y_*y_);
  float xx = r*0.2f;
  float x2 = xx*xx;
  float x5 = x2*x2*xx;
  float env = 1.f - 21.f*x5 + 35.f*x5*xx - 15.f*x5*x2;
  float pref = 0.6324555320336759f*inv*env;
  float* efp = efC + (size_t)slot*8;
  const float PI_ = 3.14159265358979323846f;
  #pragma unroll
  for (int b = 0; b < 8; b++) efp[b] = pref*sinf((float)(b+1)*PI_*xx);
}

// ---------------------------------------------------------------- radial MLP -> RC = R * s_src (CSR order)
#define ACC_ZERO() do{ _Pragma("unroll") for(int i_=0;i_<4;i_++){ _Pragma("unroll") for(int j_=0;j_<4;j_++) acc[i_][j_]=0.f; } }while(0)
#define GEMM_STEP(H,KMAX) do{ _Pragma("unroll 8") for(int k_=0;k_<KMAX;k_++){ \
  float4 h_ = *(const float4*)&H[k_*64+e4]; \
  float4 w_ = *(const float4*)&Wl[k_*64+c4]; \
  acc[0][0]+=h_.x*w_.x; acc[0][1]+=h_.x*w_.y; acc[0][2]+=h_.x*w_.z; acc[0][3]+=h_.x*w_.w; \
  acc[1][0]+=h_.y*w_.x; acc[1][1]+=h_.y*w_.y; acc[1][2]+=h_.y*w_.z; acc[1][3]+=h_.y*w_.w; \
  acc[2][0]+=h_.z*w_.x; acc[2][1]+=h_.z*w_.y; acc[2][2]+=h_.z*w_.z; acc[2][3]+=h_.z*w_.w; \
  acc[3][0]+=h_.w*w_.x; acc[3][1]+=h_.w*w_.y; acc[3][2]+=h_.w*w_.z; acc[3][3]+=h_.w*w_.w; } }while(0)
#define SILU_ACC() do{ _Pragma("unroll") for(int i_=0;i_<4;i_++){ _Pragma("unroll") for(int j_=0;j_<4;j_++) acc[i_][j_]=silu_f(acc[i_][j_]); } }while(0)
#define STORE_H(HOUT) do{ _Pragma("unroll") for(int j_=0;j_<4;j_++){ \
  *(float4*)&HOUT[(c4+j_)*64+e4] = make_float4(acc[0][j_],acc[1][j_],acc[2][j_],acc[3][j_]); } }while(0)

__global__ __launch_bounds__(256) void k_R(
    const float* __restrict__ efC, const int* __restrict__ srcC,
    const float* __restrict__ s_cur, const int* __restrict__ nact_p,
    const float* __restrict__ W1, const float* __restrict__ W2,
    const float* __restrict__ W3, const float* __restrict__ W4,
    float* __restrict__ RC)
{
  __shared__ __align__(16) float Wl[4096];
  __shared__ __align__(16) float hA[4096];
  __shared__ __align__(16) float hB[4096];
  int nact = *nact_p;
  int ebase = blockIdx.x*64;
  if (ebase >= nact) return;
  int tid = threadIdx.x;
  for (int i = tid; i < 512; i += 256){
    int eL = i>>3, b = i&7;
    int idx = ebase+eL; if (idx > nact-1) idx = nact-1;
    hA[b*64+eL] = efC[(size_t)idx*8+b];
  }
  for (int i = tid; i < 512; i += 256) Wl[i] = W1[i];
  int c4 = (tid & 15)*4, e4 = (tid >> 4)*4;
  // prefetch src rows of s_cur early (latency hidden behind MLP layers)
  int eidx[4];
  float4 sv[4];
  #pragma unroll
  for (int i = 0; i < 4; i++){
    int idx = ebase+e4+i; if (idx > nact-1) idx = nact-1;
    eidx[i] = idx;
  }
  #pragma unroll
  for (int i = 0; i < 4; i++){
    int sn = srcC[eidx[i]];
    sv[i] = *(const float4*)&s_cur[(size_t)sn*64+c4];
  }
  __syncthreads();
  float acc[4][4];
  // layer 1 (K=8) + silu
  ACC_ZERO(); GEMM_STEP(hA, 8); SILU_ACC();
  __syncthreads();
  STORE_H(hB);
  for (int i = tid; i < 1024; i += 256) ((float4*)Wl)[i] = ((const float4*)W2)[i];
  __syncthreads();
  // layer 2 + silu
  ACC_ZERO(); GEMM_STEP(hB, 64); SILU_ACC();
  __syncthreads();
  STORE_H(hA);
  for (int i = tid; i < 1024; i += 256) ((float4*)Wl)[i] = ((const float4*)W3)[i];
  __syncthreads();
  // layer 3 + silu
  ACC_ZERO(); GEMM_STEP(hA, 64); SILU_ACC();
  __syncthreads();
  STORE_H(hB);
  for (int i = tid; i < 1024; i += 256) ((float4*)Wl)[i] = ((const float4*)W4)[i];
  __syncthreads();
  // layer 4, no silu; fuse *= s_src; store CSR-ordered
  ACC_ZERO(); GEMM_STEP(hB, 64);
  #pragma unroll
  for (int i = 0; i < 4; i++){
    *(float4*)&RC[(size_t)eidx[i]*64+c4] =
      make_float4(acc[i][0]*sv[i].x, acc[i][1]*sv[i].y, acc[i][2]*sv[i].z, acc[i][3]*sv[i].w);
  }
}

// ---------------------------------------------------------------- streaming segment-sum: agg[n][m][c]
__global__ __launch_bounds__(256) void k_agg(
    const float* __restrict__ RC, const float* __restrict__ shC,
    const int* __restrict__ offs, float* __restrict__ agg)
{
  int tid = threadIdx.x;
  int wv = tid>>6, ln = tid&63;
  int n = blockIdx.x*4 + wv;
  int beg = offs[n], end = offs[n+1];
  float acc[9] = {0,0,0,0,0,0,0,0,0};
  #pragma unroll 2
  for (int p = beg; p < end; ++p){
    float rc = RC[(size_t)p*64+ln];
    const float* sp = shC + (size_t)p*12;
    float4 a0 = *(const float4*)sp;
    float4 a1 = *(const float4*)(sp+4);
    float  a8 = sp[8];
    acc[0] += rc*a0.x; acc[1] += rc*a0.y; acc[2] += rc*a0.z; acc[3] += rc*a0.w;
    acc[4] += rc*a1.x; acc[5] += rc*a1.y; acc[6] += rc*a1.z; acc[7] += rc*a1.w;
    acc[8] += rc*a8;
  }
  #pragma unroll
  for (int m = 0; m < 9; m++) agg[((size_t)n*9+m)*64+ln] = acc[m]*(1.f/24.f);
}

// ---------------------------------------------------------------- mix + product + epilogue
__global__ __launch_bounds__(256) void k_mix(
    const float* __restrict__ agg, float* __restrict__ s_nxt,
    const float* __restrict__ attrs, float* __restrict__ feats,
    const float* __restrict__ WmixT, const float* __restrict__ WscT, const float* __restrict__ w2T,
    const float* __restrict__ w3T, const float* __restrict__ WqT, const float* __restrict__ Wr0,
    const float* __restrict__ Wh, const float* __restrict__ Wo,
    float* __restrict__ out_ne, float* __restrict__ out_ctr, float* __restrict__ out_q, int t)
{
  __shared__ __align__(16) float WT[3*4160];    // [l][c*65+d]
  __shared__ __align__(16) float aggS[4][768];  // wave-private [c*12+m]
  __shared__ float f0S[4][64];
  __shared__ float hS[4][16];
  int tid = threadIdx.x;
  for (int i = tid; i < 3*64*64; i += 256){
    int l = i>>12, rem = i&4095, d = rem>>6, c = rem&63;
    WT[l*4160 + c*65 + d] = WmixT[i];
  }
  __syncthreads();
  int wv = tid>>6, ln = tid&63;
  for (int nn = 0; nn < 8; ++nn){
    int n = blockIdx.x*32 + nn*4 + wv;
    int g = n>>8;
    // stage this node's agg (wave-private LDS: no barrier needed)
    #pragma unroll
    for (int m = 0; m < 9; m++) aggS[wv][ln*12+m] = agg[((size_t)n*9+m)*64+ln];
    float mx[9] = {0,0,0,0,0,0,0,0,0};
    #pragma unroll 4
    for (int c = 0; c < 64; ++c){
      float4 a0 = *(const float4*)&aggS[wv][c*12];
      float4 a1 = *(const float4*)&aggS[wv][c*12+4];
      float a8  = aggS[wv][c*12+8];
      float w0 = WT[c*65+ln];
      float w1 = WT[4160 + c*65+ln];
      float wc = WT[8320 + c*65+ln];
      mx[0] += a0.x*w0;
      mx[1] += a0.y*w1; mx[2] += a0.z*w1; mx[3] += a0.w*w1;
      mx[4] += a1.x*wc; mx[5] += a1.y*wc; mx[6] += a1.z*wc; mx[7] += a1.w*wc;
      mx[8] += a8*wc;
    }
    float g2 = 0.f, g3 = 0.f, wsc = 0.f;
    #pragma unroll
    for (int k = 0; k < NELEM; k++){
      float a = attrs[n*NELEM+k];
      g2 += a*w2T[k*64+ln]; g3 += a*w3T[k*64+ln]; wsc += a*WscT[k*64+ln];
    }
    float s0 = mx[0];
    float factor = 1.f + g2*s0 + g3*s0*s0;
    float f0 = 0.f;
    #pragma unroll
    for (int m = 0; m < 9; m++){
      size_t idx = ((size_t)n*9+m)*64+ln;
      float fnew = mx[m]*factor + feats[idx]*wsc;
      feats[idx] = fnew;
      if (m == 0) f0 = fnew;
    }
    s_nxt[n*64+ln] = f0;
    float qv = f0*WqT[ln];
    #pragma unroll
    for (int o = 32; o > 0; o >>= 1) qv += __shfl_down(qv, o, 64);
    float nev = 0.f;
    if (t == 0){
      nev = f0*Wr0[ln];
      #pragma unroll
      for (int o = 32; o > 0; o >>= 1) nev += __shfl_down(nev, o, 64);
    }
    f0S[wv][ln] = f0;                 // wave-private: no barrier
    if (t == 1 && ln < 16){
      float h = 0.f;
      #pragma unroll 8
      for (int dd = 0; dd < 64; dd++) h += f0S[wv][dd]*Wh[dd*16+ln];
      hS[wv][ln] = silu_f(h);
    }
    if (ln == 0){
      out_q[n] += qv;
      if (t == 0){
        out_ne[n] += nev;
        atomicAdd(&out_ctr[g*3+1], nev);
      } else {
        float ne2 = 0.f;
        #pragma unroll
        for (int j = 0; j < 16; j++) ne2 += hS[wv][j]*Wo[j];
        out_ne[n] += ne2;
        atomicAdd(&out_ctr[g*3+2], ne2);
      }
    }
  }
}

// ---------------------------------------------------------------- Coulomb + dipole + total
__global__ __launch_bounds__(256) void k_coul(
    const float* __restrict__ q, const float* __restrict__ pos,
    const float* __restrict__ ctr, float* __restrict__ te, float* __restrict__ dip)
{
  __shared__ float qs[256], px[256], py[256], pz[256];
  __shared__ float red[16];
  int g = blockIdx.x, i = threadIdx.x, n = g*256+i;
  float qi = q[n];
  float xi = pos[n*3], yi = pos[n*3+1], zi = pos[n*3+2];
  qs[i] = qi; px[i] = xi; py[i] = yi; pz[i] = zi;
  __syncthreads();
  float srow = 0.f;
  for (int j = 0; j < 256; ++j){
    float dx = xi-px[j], dy = yi-py[j], dz = zi-pz[j];
    float r2 = dx*dx+dy*dy+dz*dz + 1e-12f;
    float r = sqrtf(r2);
    float v = erff(0.5f*r)/r;
    srow += (j == i) ? 0.f : qs[j]*v;
  }
  float vals[4] = { qi*srow, qi*xi, qi*yi, qi*zi };
  int wv = i>>6, ln = i&63;
  #pragma unroll
  for (int k = 0; k < 4; k++){
    float v = vals[k];
    #pragma unroll
    for (int o = 32; o > 0; o >>= 1) v += __shfl_down(v, o, 64);
    if (ln == 0) red[wv*4+k] = v;
  }
  __syncthreads();
  if (i == 0){
    float e = 0.f, dx = 0.f, dy = 0.f, dz = 0.f;
    for (int w = 0; w < 4; w++){ e += red[w*4]; dx += red[w*4+1]; dy += red[w*4+2]; dz += red[w*4+3]; }
    te[g] = ctr[g*3] + ctr[g*3+1] + ctr[g*3+2] + 0.5f*e;
    dip[g*3] = dx; dip[g*3+1] = dy; dip[g*3+2] = dz;
  }
}

// ---------------------------------------------------------------- launch
extern "C" void kernel_launch(void* const* d_in, const int* in_sizes, int n_in,
                              void* d_out, int out_size, void* d_ws, size_t ws_size,
                              hipStream_t stream)
{
  (void)in_sizes; (void)n_in; (void)out_size; (void)ws_size;
  const float* attrs   = (const float*)d_in[0];
  const float* pos     = (const float*)d_in[1];
  const int*   ei      = (const int*)d_in[2];
  const float* W_embed = (const float*)d_in[4];
  const float* E0      = (const float*)d_in[5];
  const float* rW1     = (const float*)d_in[6];
  const float* rW2     = (const float*)d_in[7];
  const float* rW3     = (const float*)d_in[8];
  const float* rW4     = (const float*)d_in[9];
  const float* Wmix    = (const float*)d_in[10];
  const float* Wsc     = (const float*)d_in[11];
  const float* w2      = (const float*)d_in[12];
  const float* w3      = (const float*)d_in[13];
  const float* Wr0     = (const float*)d_in[14];
  const float* Wh      = (const float*)d_in[15];
  const float* Wo      = (const float*)d_in[16];
  const float* Wq      = (const float*)d_in[17];

  float* ws    = (float*)d_ws;
  float* efC   = ws;                                   // NEDGE*8
  float* shC   = efC   + (size_t)NEDGE*8;              // NEDGE*12
  float* RC    = shC   + (size_t)NEDGE*12;             // NEDGE*64
  float* s_cur = RC    + (size_t)NEDGE*64;             // NNODE*64
  float* s_nxt = s_cur + (size_t)NNODE*CDIM;           // NNODE*64
  float* feats = s_nxt + (size_t)NNODE*CDIM;           // NNODE*576
  float* agg   = feats + (size_t)NNODE*CDIM*9;         // NNODE*576
  int*   deg   = (int*)(agg + (size_t)NNODE*CDIM*9);   // NNODE
  int*   offs  = deg    + NNODE;                       // NNODE+1
  int*   cursor= offs   + NNODE+1;                     // NNODE
  int*   srcC  = cursor + NNODE;                       // NEDGE

  float* out_te  = (float*)d_out;
  float* out_ne  = out_te  + NGRAPH;
  float* out_ctr = out_ne  + NNODE;
  float* out_q   = out_ctr + NGRAPH*3;
  float* out_dip = out_q   + NNODE;

  hipMemsetAsync(d_out, 0, sizeof(float)*(size_t)(NGRAPH + NNODE + NGRAPH*3 + NNODE + NGRAPH*3), stream);
  hipMemsetAsync(deg, 0, sizeof(int)*(size_t)NNODE, stream);
  hipMemsetAsync(cursor, 0, sizeof(int)*(size_t)NNODE, stream);

  k_init <<<NNODE, 64, 0, stream>>>(attrs, W_embed, E0, s_cur, feats, out_ctr, out_ne);
  k_count<<<NEDGE/256, 256, 0, stream>>>(ei, pos, deg);
  k_scan <<<1, 1024, 0, stream>>>(deg, offs);
  k_fill <<<NEDGE/256, 256, 0, stream>>>(ei, pos, offs, cursor, srcC, efC, shC);

  for (int t = 0; t < 2; t++){
    const float* scur = t ? s_nxt : s_cur;
    float*       snxt = t ? s_cur : s_nxt;
    k_R  <<<NEDGE/64, 256, 0, stream>>>(efC, srcC, scur, offs+NNODE,
        rW1 + t*8*64, rW2 + t*64*64, rW3 + t*64*64, rW4 + t*64*CDIM, RC);
    k_agg<<<NNODE/4, 256, 0, stream>>>(RC, shC, offs, agg);
    k_mix<<<NNODE/32, 256, 0, stream>>>(agg, snxt, attrs, feats,
        Wmix + t*3*64*64, Wsc + t*NELEM*CDIM, w2 + t*NELEM*CDIM,
        w3 + t*NELEM*CDIM, Wq + t*CDIM, Wr0, Wh, Wo, out_ne, out_ctr, out_q, t);
  }
  k_coul<<<NGRAPH, 256, 0, stream>>>(out_q, pos, out_ctr, out_te, out_dip);
}

// Round 3
// 493.248 us; speedup vs baseline: 1.4978x; 1.1385x over previous
//
#include <hip/hip_runtime.h>
#include <math.h>

#define NGRAPH 64
#define NPER   256
#define NNODE  (NGRAPH*NPER)      // 16384
#define CDIM   64
#define NELEM  10
#define NEDGE  (NNODE*24)         // 393216
#define RMAX2  25.0f

typedef _Float16 half8 __attribute__((ext_vector_type(8)));
typedef float floatx4 __attribute__((ext_vector_type(4)));

__device__ __forceinline__ float silu_f(float x){ return x/(1.f+__expf(-x)); }

// ---------------------------------------------------------------- init
__global__ __launch_bounds__(64) void k_init(
    const float* __restrict__ attrs, const float* __restrict__ W_embed,
    const float* __restrict__ E0, float* __restrict__ s_cur,
    float* __restrict__ feats, float* __restrict__ out_ctr, float* __restrict__ out_ne)
{
  int n = blockIdx.x, c = threadIdx.x;
  float s = 0.f;
  #pragma unroll
  for (int k = 0; k < NELEM; k++) s += attrs[n*NELEM+k]*W_embed[k*CDIM+c];
  s_cur[n*CDIM+c] = s;
  feats[(size_t)n*9*CDIM + c] = s;
  #pragma unroll
  for (int m = 1; m < 9; m++) feats[((size_t)n*9+m)*CDIM+c] = 0.f;
  if (c == 0){
    float ev = 0.f;
    #pragma unroll
    for (int k = 0; k < NELEM; k++) ev += attrs[n*NELEM+k]*E0[k];
    out_ne[n] = ev;
    atomicAdd(&out_ctr[(n>>8)*3], ev);
  }
}

// ---------------------------------------------------------------- CSR: count
__global__ __launch_bounds__(256) void k_count(
    const int* __restrict__ ei, const float* __restrict__ pos, int* __restrict__ deg)
{
  int e = blockIdx.x*256 + threadIdx.x;
  int s = ei[e], d = ei[NEDGE+e];
  float vx = pos[d*3]-pos[s*3], vy = pos[d*3+1]-pos[s*3+1], vz = pos[d*3+2]-pos[s*3+2];
  if (vx*vx+vy*vy+vz*vz < RMAX2) atomicAdd(&deg[d], 1);
}

__global__ __launch_bounds__(1024) void k_scan(const int* __restrict__ deg, int* __restrict__ offs)
{
  __shared__ int sums[1024];
  int t = threadIdx.x;
  int loc[16];
  int s = 0, base = t*16;
  #pragma unroll
  for (int i = 0; i < 16; i++){ loc[i] = s; s += deg[base+i]; }
  sums[t] = s;
  __syncthreads();
  for (int off = 1; off < 1024; off <<= 1){
    int v = (t >= off) ? sums[t-off] : 0;
    __syncthreads();
    sums[t] += v;
    __syncthreads();
  }
  int pre = (t > 0) ? sums[t-1] : 0;
  #pragma unroll
  for (int i = 0; i < 16; i++) offs[base+i] = pre + loc[i];
  if (t == 1023) offs[NNODE] = pre + s;
}

// ---------------------------------------------------------------- CSR: fill + geometry (CSR-slot order)
__global__ __launch_bounds__(256) void k_fill(
    const int* __restrict__ ei, const float* __restrict__ pos,
    const int* __restrict__ offs, int* __restrict__ cursor,
    int* __restrict__ srcC, float* __restrict__ efC, float* __restrict__ shC)
{
  int e = blockIdx.x*256 + threadIdx.x;
  int s = ei[e], d = ei[NEDGE+e];
  float vx = pos[d*3]-pos[s*3], vy = pos[d*3+1]-pos[s*3+1], vz = pos[d*3+2]-pos[s*3+2];
  float r2 = vx*vx+vy*vy+vz*vz;
  if (r2 >= RMAX2) return;
  int p = atomicAdd(&cursor[d], 1);
  int slot = offs[d] + p;
  srcC[slot] = s;
  float r = sqrtf(r2);
  float inv = 1.f/fmaxf(r, 1e-9f);
  float x_ = vx*inv, y_ = vy*inv, z_ = vz*inv;
  const float s3 = 1.7320508075688772f, s15 = 3.872983346207417f, s5 = 2.2360679774997896f;
  float* shp = shC + (size_t)slot*12;
  shp[0] = 1.f;        shp[1] = s3*x_;      shp[2] = s3*y_;       shp[3] = s3*z_;
  shp[4] = s15*x_*y_;  shp[5] = s15*y_*z_;  shp[6] = 0.5f*s5*(3.f*z_*z_-1.f);
  shp[7] = s15*x_*z_;  shp[8] = 0.5f*s15*(x_*x_-y_*y_);
  float xx = r*0.2f;
  float x2 = xx*xx;
  float x5 = x2*x2*xx;
  float env = 1.f - 21.f*x5 + 35.f*x5*xx - 15.f*x5*x2;
  float pref = 0.6324555320336759f*inv*env;
  float* efp = efC + (size_t)slot*8;
  const float PI_ = 3.14159265358979323846f;
  #pragma unroll
  for (int b = 0; b < 8; b++) efp[b] = pref*sinf((float)(b+1)*PI_*xx);
}

// ---------------------------------------------------------------- radial MLP via f16 MFMA -> RC = R*s_src
// Block = 64 CSR edges, 256 threads = 4 waves. Wave w owns channel cols [16w,16w+16).
// A (activations) in LDS [edge][k], 72-f16 row stride (36 dwords -> b128 frag reads at bank floor).
// B (weights) staged frag-linear f16: 28 frags (L1:4, L2/3/4: 8 each).
__global__ __launch_bounds__(256) void k_R(
    const float* __restrict__ efC, const int* __restrict__ srcC,
    const float* __restrict__ s_cur, const int* __restrict__ nact_p,
    const float* __restrict__ W1, const float* __restrict__ W2,
    const float* __restrict__ W3, const float* __restrict__ W4,
    float* __restrict__ RC)
{
  __shared__ __align__(16) _Float16 Wf[28*512];
  __shared__ __align__(16) _Float16 Ab[64*72];
  __shared__ int srcS[64];
  int nact = *nact_p;
  int ebase = blockIdx.x*64;
  if (ebase >= nact) return;
  int tid = threadIdx.x;
  int w = tid>>6, ln = tid&63, ln15 = ln&15, quad = ln>>4;

  // ---- stage weights as B-frags: B[k=quad*8+j][n=ln15] per 16x16x32 tile
  const float* Ws[4] = {W1, W2, W3, W4};
  for (int f = w; f < 28; f += 4){
    int l, kt, nt;
    if (f < 4){ l = 0; kt = 0; nt = f; }
    else { int g = f-4; l = 1 + g/8; int r8 = g&7; nt = r8>>1; kt = r8&1; }
    const float* Wp = Ws[l];
    half8 v;
    #pragma unroll
    for (int j = 0; j < 8; j++){
      int k = kt*32 + quad*8 + j;
      int c = nt*16 + ln15;
      float x = (l == 0) ? ((k < 8) ? Wp[k*64+c] : 0.f) : Wp[k*64+c];
      v[j] = (_Float16)x;
    }
    *(half8*)&Wf[((size_t)f*64 + ln)*8] = v;
  }

  // ---- stage ef into Ab rows (K=8 padded to 32 with zeros); wave w covers cols [8w,8w+8)
  {
    int e = ln;  // wave-local edge row
    half8 v;
    #pragma unroll
    for (int j = 0; j < 8; j++) v[j] = (_Float16)0.f;
    if (w == 0){
      int idx = ebase + e; if (idx > nact-1) idx = nact-1;
      const float* p = efC + (size_t)idx*8;
      #pragma unroll
      for (int j = 0; j < 8; j++) v[j] = (_Float16)p[j];
      srcS[e] = srcC[idx];
    }
    *(half8*)&Ab[e*72 + w*8] = v;
  }
  __syncthreads();

  // ---- prefetch s_src (consumed only at the very end; latency hidden behind MLP)
  float sv[16];
  #pragma unroll
  for (int mt = 0; mt < 4; mt++)
    #pragma unroll
    for (int r = 0; r < 4; r++){
      int el = mt*16 + quad*4 + r;
      int sn = srcS[el];
      sv[mt*4+r] = s_cur[(size_t)sn*64 + w*16 + ln15];
    }

  floatx4 zero = {0.f, 0.f, 0.f, 0.f};
  floatx4 acc[4];

  // ---- layer 1: K=32 (one step), frags 0..3
  {
    half8 bf = *(const half8*)&Wf[((size_t)(0 + w)*64 + ln)*8];
    #pragma unroll
    for (int mt = 0; mt < 4; mt++){
      half8 af = *(const half8*)&Ab[(mt*16 + ln15)*72 + quad*8];
      acc[mt] = __builtin_amdgcn_mfma_f32_16x16x32_f16(af, bf, zero, 0, 0, 0);
    }
  }
  __syncthreads();
  #pragma unroll
  for (int mt = 0; mt < 4; mt++)
    #pragma unroll
    for (int r = 0; r < 4; r++)
      Ab[(mt*16 + quad*4 + r)*72 + w*16 + ln15] = (_Float16)silu_f(acc[mt][r]);
  __syncthreads();

  // ---- layers 2..4: K=64 (two steps)
  #pragma unroll
  for (int l = 0; l < 3; l++){
    int fb = 4 + l*8;
    half8 bf0 = *(const half8*)&Wf[((size_t)(fb + w*2 + 0)*64 + ln)*8];
    half8 bf1 = *(const half8*)&Wf[((size_t)(fb + w*2 + 1)*64 + ln)*8];
    #pragma unroll
    for (int mt = 0; mt < 4; mt++){
      half8 a0 = *(const half8*)&Ab[(mt*16 + ln15)*72 + quad*8];
      half8 a1 = *(const half8*)&Ab[(mt*16 + ln15)*72 + 32 + quad*8];
      floatx4 t = __builtin_amdgcn_mfma_f32_16x16x32_f16(a0, bf0, zero, 0, 0, 0);
      acc[mt] = __builtin_amdgcn_mfma_f32_16x16x32_f16(a1, bf1, t, 0, 0, 0);
    }
    __syncthreads();
    if (l < 2){
      #pragma unroll
      for (int mt = 0; mt < 4; mt++)
        #pragma unroll
        for (int r = 0; r < 4; r++)
          Ab[(mt*16 + quad*4 + r)*72 + w*16 + ln15] = (_Float16)silu_f(acc[mt][r]);
      __syncthreads();
    }
  }

  // ---- epilogue: RC[e][c] = R * s_src   (no silu on layer 4)
  #pragma unroll
  for (int mt = 0; mt < 4; mt++)
    #pragma unroll
    for (int r = 0; r < 4; r++){
      int el = mt*16 + quad*4 + r;
      int idx = ebase + el; if (idx > nact-1) idx = nact-1;
      RC[(size_t)idx*64 + w*16 + ln15] = acc[mt][r] * sv[mt*4+r];
    }
}

// ---------------------------------------------------------------- streaming segment-sum: agg[n][m][c]
__global__ __launch_bounds__(256) void k_agg(
    const float* __restrict__ RC, const float* __restrict__ shC,
    const int* __restrict__ offs, float* __restrict__ agg)
{
  int tid = threadIdx.x;
  int wv = tid>>6, ln = tid&63;
  int n = blockIdx.x*4 + wv;
  int beg = offs[n], end = offs[n+1];
  float acc[9] = {0,0,0,0,0,0,0,0,0};
  #pragma unroll 2
  for (int p = beg; p < end; ++p){
    float rc = RC[(size_t)p*64+ln];
    const float* sp = shC + (size_t)p*12;
    float4 a0 = *(const float4*)sp;
    float4 a1 = *(const float4*)(sp+4);
    float  a8 = sp[8];
    acc[0] += rc*a0.x; acc[1] += rc*a0.y; acc[2] += rc*a0.z; acc[3] += rc*a0.w;
    acc[4] += rc*a1.x; acc[5] += rc*a1.y; acc[6] += rc*a1.z; acc[7] += rc*a1.w;
    acc[8] += rc*a8;
  }
  #pragma unroll
  for (int m = 0; m < 9; m++) agg[((size_t)n*9+m)*64+ln] = acc[m]*(1.f/24.f);
}

// ---------------------------------------------------------------- mix + product + epilogue
__global__ __launch_bounds__(256) void k_mix(
    const float* __restrict__ agg, float* __restrict__ s_nxt,
    const float* __restrict__ attrs, float* __restrict__ feats,
    const float* __restrict__ WmixT, const float* __restrict__ WscT, const float* __restrict__ w2T,
    const float* __restrict__ w3T, const float* __restrict__ WqT, const float* __restrict__ Wr0,
    const float* __restrict__ Wh, const float* __restrict__ Wo,
    float* __restrict__ out_ne, float* __restrict__ out_ctr, float* __restrict__ out_q, int t)
{
  __shared__ __align__(16) float WT[3*4160];    // [l][c*65+d]
  __shared__ __align__(16) float aggS[4][768];  // wave-private [c*12+m]
  __shared__ float f0S[4][64];
  __shared__ float hS[4][16];
  int tid = threadIdx.x;
  for (int i = tid; i < 3*64*64; i += 256){
    int l = i>>12, rem = i&4095, d = rem>>6, c = rem&63;
    WT[l*4160 + c*65 + d] = WmixT[i];
  }
  __syncthreads();
  int wv = tid>>6, ln = tid&63;
  for (int nn = 0; nn < 8; ++nn){
    int n = blockIdx.x*32 + nn*4 + wv;
    int g = n>>8;
    #pragma unroll
    for (int m = 0; m < 9; m++) aggS[wv][ln*12+m] = agg[((size_t)n*9+m)*64+ln];
    float mx[9] = {0,0,0,0,0,0,0,0,0};
    #pragma unroll 4
    for (int c = 0; c < 64; ++c){
      float4 a0 = *(const float4*)&aggS[wv][c*12];
      float4 a1 = *(const float4*)&aggS[wv][c*12+4];
      float a8  = aggS[wv][c*12+8];
      float w0 = WT[c*65+ln];
      float w1 = WT[4160 + c*65+ln];
      float wc = WT[8320 + c*65+ln];
      mx[0] += a0.x*w0;
      mx[1] += a0.y*w1; mx[2] += a0.z*w1; mx[3] += a0.w*w1;
      mx[4] += a1.x*wc; mx[5] += a1.y*wc; mx[6] += a1.z*wc; mx[7] += a1.w*wc;
      mx[8] += a8*wc;
    }
    float g2 = 0.f, g3 = 0.f, wsc = 0.f;
    #pragma unroll
    for (int k = 0; k < NELEM; k++){
      float a = attrs[n*NELEM+k];
      g2 += a*w2T[k*64+ln]; g3 += a*w3T[k*64+ln]; wsc += a*WscT[k*64+ln];
    }
    float s0 = mx[0];
    float factor = 1.f + g2*s0 + g3*s0*s0;
    float f0 = 0.f;
    #pragma unroll
    for (int m = 0; m < 9; m++){
      size_t idx = ((size_t)n*9+m)*64+ln;
      float fnew = mx[m]*factor + feats[idx]*wsc;
      feats[idx] = fnew;
      if (m == 0) f0 = fnew;
    }
    s_nxt[n*64+ln] = f0;
    float qv = f0*WqT[ln];
    #pragma unroll
    for (int o = 32; o > 0; o >>= 1) qv += __shfl_down(qv, o, 64);
    float nev = 0.f;
    if (t == 0){
      nev = f0*Wr0[ln];
      #pragma unroll
      for (int o = 32; o > 0; o >>= 1) nev += __shfl_down(nev, o, 64);
    }
    f0S[wv][ln] = f0;
    if (t == 1 && ln < 16){
      float h = 0.f;
      #pragma unroll 8
      for (int dd = 0; dd < 64; dd++) h += f0S[wv][dd]*Wh[dd*16+ln];
      hS[wv][ln] = silu_f(h);
    }
    if (ln == 0){
      out_q[n] += qv;
      if (t == 0){
        out_ne[n] += nev;
        atomicAdd(&out_ctr[g*3+1], nev);
      } else {
        float ne2 = 0.f;
        #pragma unroll
        for (int j = 0; j < 16; j++) ne2 += hS[wv][j]*Wo[j];
        out_ne[n] += ne2;
        atomicAdd(&out_ctr[g*3+2], ne2);
      }
    }
  }
}

// ---------------------------------------------------------------- Coulomb + dipole + total
__global__ __launch_bounds__(256) void k_coul(
    const float* __restrict__ q, const float* __restrict__ pos,
    const float* __restrict__ ctr, float* __restrict__ te, float* __restrict__ dip)
{
  __shared__ float qs[256], px[256], py[256], pz[256];
  __shared__ float red[16];
  int g = blockIdx.x, i = threadIdx.x, n = g*256+i;
  float qi = q[n];
  float xi = pos[n*3], yi = pos[n*3+1], zi = pos[n*3+2];
  qs[i] = qi; px[i] = xi; py[i] = yi; pz[i] = zi;
  __syncthreads();
  float srow = 0.f;
  for (int j = 0; j < 256; ++j){
    float dx = xi-px[j], dy = yi-py[j], dz = zi-pz[j];
    float r2 = dx*dx+dy*dy+dz*dz + 1e-12f;
    float r = sqrtf(r2);
    float v = erff(0.5f*r)/r;
    srow += (j == i) ? 0.f : qs[j]*v;
  }
  float vals[4] = { qi*srow, qi*xi, qi*yi, qi*zi };
  int wv = i>>6, ln = i&63;
  #pragma unroll
  for (int k = 0; k < 4; k++){
    float v = vals[k];
    #pragma unroll
    for (int o = 32; o > 0; o >>= 1) v += __shfl_down(v, o, 64);
    if (ln == 0) red[wv*4+k] = v;
  }
  __syncthreads();
  if (i == 0){
    float e = 0.f, dx = 0.f, dy = 0.f, dz = 0.f;
    for (int w = 0; w < 4; w++){ e += red[w*4]; dx += red[w*4+1]; dy += red[w*4+2]; dz += red[w*4+3]; }
    te[g] = ctr[g*3] + ctr[g*3+1] + ctr[g*3+2] + 0.5f*e;
    dip[g*3] = dx; dip[g*3+1] = dy; dip[g*3+2] = dz;
  }
}

// ---------------------------------------------------------------- launch
extern "C" void kernel_launch(void* const* d_in, const int* in_sizes, int n_in,
                              void* d_out, int out_size, void* d_ws, size_t ws_size,
                              hipStream_t stream)
{
  (void)in_sizes; (void)n_in; (void)out_size; (void)ws_size;
  const float* attrs   = (const float*)d_in[0];
  const float* pos     = (const float*)d_in[1];
  const int*   ei      = (const int*)d_in[2];
  const float* W_embed = (const float*)d_in[4];
  const float* E0      = (const float*)d_in[5];
  const float* rW1     = (const float*)d_in[6];
  const float* rW2     = (const float*)d_in[7];
  const float* rW3     = (const float*)d_in[8];
  const float* rW4     = (const float*)d_in[9];
  const float* Wmix    = (const float*)d_in[10];
  const float* Wsc     = (const float*)d_in[11];
  const float* w2      = (const float*)d_in[12];
  const float* w3      = (const float*)d_in[13];
  const float* Wr0     = (const float*)d_in[14];
  const float* Wh      = (const float*)d_in[15];
  const float* Wo      = (const float*)d_in[16];
  const float* Wq      = (const float*)d_in[17];

  float* ws    = (float*)d_ws;
  float* efC   = ws;                                   // NEDGE*8
  float* shC   = efC   + (size_t)NEDGE*8;              // NEDGE*12
  float* RC    = shC   + (size_t)NEDGE*12;             // NEDGE*64
  float* s_cur = RC    + (size_t)NEDGE*64;             // NNODE*64
  float* s_nxt = s_cur + (size_t)NNODE*CDIM;           // NNODE*64
  float* feats = s_nxt + (size_t)NNODE*CDIM;           // NNODE*576
  float* agg   = feats + (size_t)NNODE*CDIM*9;         // NNODE*576
  int*   deg   = (int*)(agg + (size_t)NNODE*CDIM*9);   // NNODE
  int*   offs  = deg    + NNODE;                       // NNODE+1
  int*   cursor= offs   + NNODE+1;                     // NNODE
  int*   srcC  = cursor + NNODE;                       // NEDGE

  float* out_te  = (float*)d_out;
  float* out_ne  = out_te  + NGRAPH;
  float* out_ctr = out_ne  + NNODE;
  float* out_q   = out_ctr + NGRAPH*3;
  float* out_dip = out_q   + NNODE;

  hipMemsetAsync(d_out, 0, sizeof(float)*(size_t)(NGRAPH + NNODE + NGRAPH*3 + NNODE + NGRAPH*3), stream);
  hipMemsetAsync(deg, 0, sizeof(int)*(size_t)NNODE, stream);
  hipMemsetAsync(cursor, 0, sizeof(int)*(size_t)NNODE, stream);

  k_init <<<NNODE, 64, 0, stream>>>(attrs, W_embed, E0, s_cur, feats, out_ctr, out_ne);
  k_count<<<NEDGE/256, 256, 0, stream>>>(ei, pos, deg);
  k_scan <<<1, 1024, 0, stream>>>(deg, offs);
  k_fill <<<NEDGE/256, 256, 0, stream>>>(ei, pos, offs, cursor, srcC, efC, shC);

  for (int t = 0; t < 2; t++){
    const float* scur = t ? s_nxt : s_cur;
    float*       snxt = t ? s_cur : s_nxt;
    k_R  <<<NEDGE/64, 256, 0, stream>>>(efC, srcC, scur, offs+NNODE,
        rW1 + t*8*64, rW2 + t*64*64, rW3 + t*64*64, rW4 + t*64*CDIM, RC);
    k_agg<<<NNODE/4, 256, 0, stream>>>(RC, shC, offs, agg);
    k_mix<<<NNODE/32, 256, 0, stream>>>(agg, snxt, attrs, feats,
        Wmix + t*3*64*64, Wsc + t*NELEM*CDIM, w2 + t*NELEM*CDIM,
        w3 + t*NELEM*CDIM, Wq + t*CDIM, Wr0, Wh, Wo, out_ne, out_ctr, out_q, t);
  }
  k_coul<<<NGRAPH, 256, 0, stream>>>(out_q, pos, out_ctr, out_te, out_dip);
}